// Round 8
// baseline (283.556 us; speedup 1.0000x reference)
//
#include <hip/hip_runtime.h>
#include <math.h>

// Problem constants (B=128, S=4096, M=20)
#define BB 128
#define SS 4096
#define MM 20
#define NPOS (BB * SS)              // 524288
#define BLOCK 256
#define CHUNK 64                    // positions per chunk (1280 components)
#define CPB 4                       // chunks per block
#define GRID (NPOS / (CHUNK * CPB)) // 2048 blocks -> 8 blocks/CU, 32 waves/CU

__device__ __forceinline__ float fast_rcp(float x) { return __builtin_amdgcn_rcpf(x); }

// Phase A: component-per-lane, fully coalesced global reads (4-12B lane
// stride), results transposed through LDS. Phase B: 4 threads/position do
// the logsumexp from LDS (5*lane word index -> 2-way bank alias = free).
// No DMA barriers, low VGPR + 10.6KB LDS -> 8 blocks/CU for latency hiding.
__global__ __launch_bounds__(BLOCK) void sketch_main(
    const float* __restrict__ xs,        // (B,S,5)
    const float* __restrict__ logits,    // (B,S,20)
    const float* __restrict__ mus,       // (B,S,20,2)
    const float* __restrict__ sigmas,    // (B,S,20,3)
    const float* __restrict__ pen_pred,  // (B,S,3)
    float* __restrict__ partials)        // (GRID)
{
    const float LOG_2PI = 1.8378770664093453f;
    __shared__ float avb[CHUNK * MM];    // 1280 floats: component log-probs
    __shared__ float lgb[CHUNK * MM];    // 1280 floats: logits copy
    __shared__ float relx[CHUNK], rely[CHUNK];
    __shared__ float red[BLOCK / 64];

    const int tid = threadIdx.x;
    float acc = 0.0f;

    for (int k = 0; k < CPB; ++k) {
        const int base = blockIdx.x * (CHUNK * CPB) + k * CHUNK;

        // ---- rel offsets (wave0 lanes 0-63) and pen term (wave1) ----
        if (tid < CHUNK) {
            const int p = base + tid;
            const float* xp = xs + (size_t)p * 5;
            float rx = xp[0], ry = xp[1];
            if ((p & (SS - 1)) != 0) { rx -= xp[-5]; ry -= xp[-4]; }
            relx[tid] = rx; rely[tid] = ry;
        } else if (tid < 2 * CHUNK) {
            const int p = base + (tid - CHUNK);
            const float* xp = xs + (size_t)p * 5;
            float pt0 = xp[2], pt1 = xp[3], pt2 = xp[4];
            float pm = fmaxf(pt0, fmaxf(pt1, pt2));
            float l3 = pm + __logf(__expf(pt0-pm) + __expf(pt1-pm) + __expf(pt2-pm));
            const float* pp = pen_pred + (size_t)p * 3;
            acc -= (pp[0]*(pt0-l3) + pp[1]*(pt1-l3) + pp[2]*(pt2-l3))
                   * (1.0f / (float)NPOS);
        }
        __syncthreads();

        // ---- phase A: 5 rounds, lane handles component c = r*256+tid ----
        const float* Sg = sigmas + (size_t)base * 60;
        const float* Mg = mus    + (size_t)base * 40;
        const float* Lg = logits + (size_t)base * 20;

        float v00[5], v10[5], v11[5], vm0[5], vm1[5], vlg[5];
#pragma unroll
        for (int r = 0; r < 5; ++r) {        // all 30 loads issued up front
            int c = r * BLOCK + tid;
            v00[r] = Sg[3*c];  v10[r] = Sg[3*c+1];  v11[r] = Sg[3*c+2];
            vm0[r] = Mg[2*c];  vm1[r] = Mg[2*c+1];
            vlg[r] = Lg[c];
        }
#pragma unroll
        for (int r = 0; r < 5; ++r) {
            int c = r * BLOCK + tid;
            int pl = c / 20;                 // magic-mul div by constant
            float rx = relx[pl], ry = rely[pl];
            float z0 = (rx - vm0[r]) * fast_rcp(v00[r]);
            float z1 = ((ry - vm1[r]) - v10[r] * z0) * fast_rcp(v11[r]);
            avb[c] = vlg[r] - 0.5f * (z0*z0 + z1*z1) - LOG_2PI
                     - __logf(v00[r] * v11[r]);
            lgb[c] = vlg[r];
        }
        __syncthreads();

        // ---- phase B: 4 threads per position, 5 components each ----
        const int pos = tid >> 2, sub = tid & 3;
        const float* A = avb + pos * MM + sub * 5;   // word idx = 5*lane
        const float* G = lgb + pos * MM + sub * 5;
        float a0=A[0], a1=A[1], a2=A[2], a3=A[3], a4=A[4];
        float mx = fmaxf(fmaxf(fmaxf(a0,a1), fmaxf(a2,a3)), a4);
        float se = __expf(a0-mx)+__expf(a1-mx)+__expf(a2-mx)
                 + __expf(a3-mx)+__expf(a4-mx);
        float sel = __expf(G[0])+__expf(G[1])+__expf(G[2])
                  + __expf(G[3])+__expf(G[4]);   // logits ~ N(0,1): safe

#pragma unroll
        for (int off = 1; off <= 2; off <<= 1) {   // merge the 4 sub-partials
            float omx = __shfl_xor(mx, off, 64);
            float ose = __shfl_xor(se, off, 64);
            float osl = __shfl_xor(sel, off, 64);
            float nm = fmaxf(mx, omx);
            se = se * __expf(mx - nm) + ose * __expf(omx - nm);
            mx = nm;
            sel += osl;
        }
        if (sub == 0) acc -= (mx + __logf(se)) - __logf(sel);
        __syncthreads();   // protect LDS before next chunk rewrites
    }

    // ---- block reduction ----
#pragma unroll
    for (int off = 32; off > 0; off >>= 1) acc += __shfl_down(acc, off, 64);
    if ((tid & 63) == 0) red[tid >> 6] = acc;
    __syncthreads();
    if (tid == 0) partials[blockIdx.x] = red[0] + red[1] + red[2] + red[3];
}

__global__ __launch_bounds__(256) void sketch_reduce(
    const float* __restrict__ partials, float* __restrict__ out)
{
    float v = 0.0f;
    for (int i = threadIdx.x; i < GRID; i += 256) v += partials[i];
#pragma unroll
    for (int off = 32; off > 0; off >>= 1) v += __shfl_down(v, off, 64);
    __shared__ float red[4];
    int lane = threadIdx.x & 63, wid = threadIdx.x >> 6;
    if (lane == 0) red[wid] = v;
    __syncthreads();
    if (threadIdx.x == 0)
        out[0] = red[0] + red[1] + red[2] + red[3];
}

extern "C" void kernel_launch(void* const* d_in, const int* in_sizes, int n_in,
                              void* d_out, int out_size, void* d_ws, size_t ws_size,
                              hipStream_t stream) {
    const float* xs       = (const float*)d_in[0];
    const float* logits   = (const float*)d_in[1];
    const float* mus      = (const float*)d_in[2];
    const float* sigmas   = (const float*)d_in[3];
    const float* pen_pred = (const float*)d_in[4];
    float* out = (float*)d_out;
    float* partials = (float*)d_ws;   // GRID floats = 8 KB

    sketch_main<<<GRID, BLOCK, 0, stream>>>(xs, logits, mus, sigmas, pen_pred, partials);
    sketch_reduce<<<1, 256, 0, stream>>>(partials, out);
}